// Round 2
// baseline (502.946 us; speedup 1.0000x reference)
//
#include <hip/hip_runtime.h>
#include <stdint.h>

#define N_TOK   4096
#define DMODEL  1024
#define DFF     2048
#define N_EXP   8
#define N_SLOTS (N_TOK * 2)        // 8192 (every token has exactly 2 expert slots)
#define ROWS_PAD (N_SLOTS + 128)   // padding so tile-tail OOB reads stay in-bounds
#define MAX_TILES 72               // sum ceil(cnt_e/128) <= 71 for any routing

typedef __bf16 bf16x8 __attribute__((ext_vector_type(8)));
typedef float  f32x4  __attribute__((ext_vector_type(4)));
typedef unsigned short u16;
typedef unsigned short u16x4 __attribute__((ext_vector_type(4)));

__device__ __forceinline__ u16 f2bf(float f) {
    union { float f; uint32_t u; } v; v.f = f;
    uint32_t r = v.u + 0x7FFFu + ((v.u >> 16) & 1u);  // RTNE
    return (u16)(r >> 16);
}
__device__ __forceinline__ float bf2f(u16 u) {
    union { uint32_t u; float f; } v; v.u = ((uint32_t)u) << 16;
    return v.f;
}

// hw packed f32->bf16 (RTNE, same values as f2bf); 2 instr per float4 vs 16 sw ops
__device__ __forceinline__ u16x4 f2bf4(float4 a) {
    union { uint32_t w[2]; u16x4 o; } u;
    asm("v_cvt_pk_bf16_f32 %0, %1, %2" : "=v"(u.w[0]) : "v"(a.x), "v"(a.y));
    asm("v_cvt_pk_bf16_f32 %0, %1, %2" : "=v"(u.w[1]) : "v"(a.z), "v"(a.w));
    return u.o;
}

// async 16B/lane global->LDS. LDS dest is wave-uniform base + lane*16 (m104 caveat).
__device__ __forceinline__ void g2l16(const void* gp, void* lp) {
    auto g = reinterpret_cast<const __attribute__((address_space(1))) unsigned int*>(
        reinterpret_cast<uintptr_t>(gp));
    auto l = reinterpret_cast<__attribute__((address_space(3))) unsigned int*>(
        reinterpret_cast<uintptr_t>(lp));
    __builtin_amdgcn_global_load_lds(g, l, 16, 0, 0);
}

// ---- XOR swizzle for 64-u16-wide (128B-row) LDS tiles: 8 col-blocks of 16B ----
// slot(r,cb) = cb ^ (r&7). Verified R6/R7: SQ_LDS_BANK_CONFLICT == 0.
// R9: reg-staged writes store src block cb at idx64(r,cb) -> identical LDS image
// to the pre-swizzled-source g2l16 path (LDS[r][b] = src block b^(r&7)).
__device__ __forceinline__ int idx64(int r, int cb) {
    return r * 64 + ((cb ^ (r & 7)) * 8);
}

// ---------------- router (standalone; R9 removed the 98us weight-cvt pass) -------------
#define RTR_BLOCKS (N_TOK / 4)                    // 1024 (4 waves/block, 1 token/wave)

__global__ void router_kernel(const float* __restrict__ x, const float* __restrict__ rw,
                              float* __restrict__ logits, int* __restrict__ tok_expert,
                              float* __restrict__ tok_gate) {
    int t = blockIdx.x * 4 + (threadIdx.x >> 6);
    int lane = threadIdx.x & 63;
    const float* xr = x + (size_t)t * DMODEL;
    float acc[N_EXP];
#pragma unroll
    for (int e = 0; e < N_EXP; ++e) acc[e] = 0.f;
    for (int i = 0; i < DMODEL / 64; ++i) {
        int k = lane + i * 64;
        float xv = xr[k];
#pragma unroll
        for (int e = 0; e < N_EXP; ++e) acc[e] += xv * rw[e * DMODEL + k];
    }
#pragma unroll
    for (int e = 0; e < N_EXP; ++e) {
        float v = acc[e];
        for (int off = 32; off > 0; off >>= 1) v += __shfl_down(v, off, 64);
        acc[e] = v;
    }
    if (lane == 0) {
        float* lg = logits + (size_t)t * N_EXP;
#pragma unroll
        for (int e = 0; e < N_EXP; ++e) lg[e] = acc[e];
        int e0 = 0; float v0 = acc[0];
#pragma unroll
        for (int e = 1; e < N_EXP; ++e) if (acc[e] > v0) { v0 = acc[e]; e0 = e; }
        int e1 = -1; float v1 = -3.0e38f;
#pragma unroll
        for (int e = 0; e < N_EXP; ++e) if (e != e0 && acc[e] > v1) { v1 = acc[e]; e1 = e; }
        float ex = expf(v1 - v0);
        tok_expert[t * 2 + 0] = e0;  tok_gate[t * 2 + 0] = 1.0f / (1.0f + ex);
        tok_expert[t * 2 + 1] = e1;  tok_gate[t * 2 + 1] = ex / (1.0f + ex);
    }
}

// ---------------- scan: counting sort -> offs[], inv[], flat m-tile table ----------------
// One block, 256 threads, atomic-free. tiletab[0] = ntiles; entry i at [4+4i]:
// {expert, row0, rows, pad}. Uniform per-block work for both GEMMs (no dead blocks,
// no mt-loop imbalance, correct under any expert skew).
__global__ void scan_kernel(const int* __restrict__ tok_expert, int* __restrict__ offs,
                            int* __restrict__ inv, int* __restrict__ tiletab) {
    __shared__ int cnt[N_EXP][257];   // [e][t] per-thread counts; [e][256] = expert total
    __shared__ int soffs[N_EXP];
    int tid = threadIdx.x;            // 256
    int base = tid * 32;
    int loc[N_EXP];
#pragma unroll
    for (int e = 0; e < N_EXP; ++e) loc[e] = 0;
    for (int i = 0; i < 32; ++i) {
        int ex = tok_expert[base + i];
#pragma unroll
        for (int e = 0; e < N_EXP; ++e) loc[e] += (ex == e);
    }
#pragma unroll
    for (int e = 0; e < N_EXP; ++e) cnt[e][tid] = loc[e];
    __syncthreads();
    if (tid < N_EXP) {                // serial exclusive prefix over 256 thread-counts
        int running = 0;
        for (int t = 0; t < 256; ++t) { int c = cnt[tid][t]; cnt[tid][t] = running; running += c; }
        cnt[tid][256] = running;
    }
    __syncthreads();
    if (tid == 0) {
        int s = 0;
        for (int e = 0; e < N_EXP; ++e) { offs[e] = s; soffs[e] = s; s += cnt[e][256]; }
        offs[N_EXP] = s;
        int n = 0;
        for (int e = 0; e < N_EXP; ++e) {
            int c = cnt[e][256];
            int r0 = soffs[e];
            for (int m = 0; m * 128 < c; ++m) {
                int rem = c - m * 128;
                tiletab[4 + n * 4 + 0] = e;
                tiletab[4 + n * 4 + 1] = r0 + m * 128;
                tiletab[4 + n * 4 + 2] = rem < 128 ? rem : 128;
                ++n;
            }
        }
        tiletab[0] = n;
    }
    __syncthreads();
#pragma unroll
    for (int e = 0; e < N_EXP; ++e) loc[e] = 0;   // reuse as local rank counters
    for (int i = 0; i < 32; ++i) {
        int ex = tok_expert[base + i];
        int row = 0;
#pragma unroll
        for (int e = 0; e < N_EXP; ++e)
            if (ex == e) { row = soffs[e] + cnt[e][tid] + loc[e]; loc[e]++; }
        inv[base + i] = row;
    }
}

// ---------------- gather: pure copy, one block per TOKEN (x row read once) ----------------
__global__ void gather_kernel(const float* __restrict__ x, const int* __restrict__ inv,
                              u16* __restrict__ Abf) {
    int t = blockIdx.x;                   // token
    int r0 = inv[t * 2];
    int r1 = inv[t * 2 + 1];
    float4 v = ((const float4*)(x + (size_t)t * DMODEL))[threadIdx.x];
    u16x4 o = { f2bf(v.x), f2bf(v.y), f2bf(v.z), f2bf(v.w) };
    *(u16x4*)(Abf + (size_t)r0 * DMODEL + threadIdx.x * 4) = o;
    *(u16x4*)(Abf + (size_t)r1 * DMODEL + threadIdx.x * 4) = o;
}

// ---------------- GEMM1: act = silu(A @ Win1^T) * (A @ Win2^T) ----------------
// BM=128 x BN=64 act-cols (x2 SwiGLU halves), BK=64. One m-tile per block via tiletab.
// Grid MAX_TILES x 32 nt (nt fastest: adjacent blocks share the A-tile in L2).
// R9: B staged from fp32 win directly (reg: global_load_dwordx4 -> cvt_pk -> ds_write),
// eliminating the separate weight-cvt dispatch. launch_bounds 4->3 (staging regs).
__global__ __launch_bounds__(256, 3)
void gemm1_kernel(const u16* __restrict__ Abf, const float* __restrict__ win,
                  u16* __restrict__ act, const int* __restrict__ tiletab) {
    int bid = blockIdx.x;
    int nt = bid & 31;
    int ti = bid >> 5;
    if (ti >= tiletab[0]) return;
    int e    = tiletab[4 + ti * 4 + 0];
    int row0 = tiletab[4 + ti * 4 + 1];
    int mmax = tiletab[4 + ti * 4 + 2];
    int n0 = nt * 64;
    const float* wsrc = win + (size_t)e * (2 * DFF) * DMODEL;

    __shared__ u16 lsA[128 * 64];
    __shared__ u16 lsB[2][64 * 64];

    int tid = threadIdx.x, lane = tid & 63, wave = tid >> 6;
    int wm = wave >> 1, wn = wave & 1;
    int s_r8 = lane >> 3;                       // row within 8-row chunk (A g2l16 path)
    int s_cb = ((lane & 7) ^ (lane >> 3)) * 8;  // swizzled source col-block (elements)
    int lr4 = lane >> 4;                        // B reg-stage: row within 4-row group
    int lc  = lane & 15;                        // B reg-stage: float4 col index
    int cbs = lc >> 1;                          // B reg-stage: source col block
    int hf  = (lane & 1) * 4;                   // B reg-stage: 8B half within 16B block

    f32x4 acc[2][4][2];
    f32x4 zero = {0.f, 0.f, 0.f, 0.f};
#pragma unroll
    for (int h = 0; h < 2; ++h)
#pragma unroll
        for (int mi = 0; mi < 4; ++mi)
#pragma unroll
            for (int ni = 0; ni < 2; ++ni) acc[h][mi][ni] = zero;

    for (int kk = 0; kk < DMODEL / 64; ++kk) {
        int k0 = kk * 64;
        // B: fp32 loads first (older in vmcnt order -> cvt can start while A g2l16 flies)
        float4 v[2][4];
#pragma unroll
        for (int h = 0; h < 2; ++h)
#pragma unroll
            for (int q2 = 0; q2 < 4; ++q2)
                v[h][q2] = *(const float4*)(wsrc +
                    (size_t)(h * DFF + n0 + wave * 16 + q2 * 4 + lr4) * DMODEL + k0 + lc * 4);
        // A: async bf16 global->LDS
#pragma unroll
        for (int q = 0; q < 4; ++q) {
            int R0 = wave * 32 + q * 8;
            g2l16(Abf + (size_t)(row0 + R0 + s_r8) * DMODEL + k0 + s_cb, &lsA[R0 * 64]);
        }
        // B: cvt + swizzled LDS write
#pragma unroll
        for (int h = 0; h < 2; ++h)
#pragma unroll
            for (int q2 = 0; q2 < 4; ++q2) {
                int r = wave * 16 + q2 * 4 + lr4;
                *(u16x4*)&lsB[h][idx64(r, cbs) + hf] = f2bf4(v[h][q2]);
            }
        __syncthreads();
#pragma unroll
        for (int kh = 0; kh < 2; ++kh) {
            int cb = kh * 4 + (lane >> 4);
            bf16x8 afr[4];
#pragma unroll
            for (int mi = 0; mi < 4; ++mi)
                afr[mi] = *(const bf16x8*)&lsA[idx64(wm * 64 + mi * 16 + (lane & 15), cb)];
#pragma unroll
            for (int h = 0; h < 2; ++h)
#pragma unroll
                for (int ni = 0; ni < 2; ++ni) {
                    bf16x8 bfr = *(const bf16x8*)&lsB[h][idx64(wn * 32 + ni * 16 + (lane & 15), cb)];
#pragma unroll
                    for (int mi = 0; mi < 4; ++mi)
                        acc[h][mi][ni] = __builtin_amdgcn_mfma_f32_16x16x32_bf16(
                            afr[mi], bfr, acc[h][mi][ni], 0, 0, 0);
                }
        }
        __syncthreads();
    }
    // epilogue: act = silu(h1) * h2, store bf16
#pragma unroll
    for (int mi = 0; mi < 4; ++mi)
#pragma unroll
        for (int i = 0; i < 4; ++i) {
            int rl = wm * 64 + mi * 16 + (lane >> 4) * 4 + i;
            if (rl < mmax) {
                size_t rp = (size_t)(row0 + rl) * DFF;
#pragma unroll
                for (int ni = 0; ni < 2; ++ni) {
                    int col = n0 + wn * 32 + ni * 16 + (lane & 15);
                    float a = acc[0][mi][ni][i];
                    float b = acc[1][mi][ni][i];
                    float sv = a / (1.0f + __expf(-a));
                    act[rp + col] = f2bf(sv * b);
                }
            }
        }
}

// ---------------- GEMM2: y = act @ Wout^T, split-K=2, bf16 stores ----------------
// BM=128 x BN=128, BK=64, K=1024 per kc. One m-tile per block via tiletab.
// Grid MAX_TILES x 8 nt x 2 kc (nt/kc fastest: 16 adjacent blocks share the act-tile).
// R9: B staged from fp32 wout directly (same reg-stage as gemm1).
__global__ __launch_bounds__(256, 3)
void gemm2_kernel(const u16* __restrict__ act, const float* __restrict__ wout,
                  u16* __restrict__ ybA, u16* __restrict__ ybB,
                  const int* __restrict__ tiletab) {
    int bid = blockIdx.x;
    int kc = bid & 1;
    int nt = (bid >> 1) & 7;
    int ti = bid >> 4;
    if (ti >= tiletab[0]) return;
    int e    = tiletab[4 + ti * 4 + 0];
    int row0 = tiletab[4 + ti * 4 + 1];
    int mmax = tiletab[4 + ti * 4 + 2];
    int n0 = nt * 128;
    const float* wsrc = wout + (size_t)e * DMODEL * DFF;

    __shared__ u16 lsA[128 * 64];
    __shared__ u16 lsB[128 * 64];

    int tid = threadIdx.x, lane = tid & 63, wave = tid >> 6;
    int wm = wave >> 1, wn = wave & 1;
    int s_r8 = lane >> 3;
    int s_cb = ((lane & 7) ^ (lane >> 3)) * 8;
    int lr4 = lane >> 4;
    int lc  = lane & 15;
    int cbs = lc >> 1;
    int hf  = (lane & 1) * 4;
    u16* yb = kc ? ybB : ybA;

    f32x4 acc[4][4];
    f32x4 zero = {0.f, 0.f, 0.f, 0.f};
#pragma unroll
    for (int mi = 0; mi < 4; ++mi)
#pragma unroll
        for (int ni = 0; ni < 4; ++ni) acc[mi][ni] = zero;

    for (int kk = kc * 16; kk < kc * 16 + 16; ++kk) {
        int k0 = kk * 64;
        // B: fp32 loads (2 batches of 4 to bound live regs)
#pragma unroll
        for (int g = 0; g < 2; ++g) {
            float4 v[4];
#pragma unroll
            for (int q2 = 0; q2 < 4; ++q2)
                v[q2] = *(const float4*)(wsrc +
                    (size_t)(n0 + wave * 32 + g * 16 + q2 * 4 + lr4) * DFF + k0 + lc * 4);
            if (g == 0) {
                // A: async bf16 global->LDS (issued after batch-0 loads, before cvt)
#pragma unroll
                for (int q = 0; q < 4; ++q) {
                    int R0 = wave * 32 + q * 8;
                    g2l16(act + (size_t)(row0 + R0 + s_r8) * DFF + k0 + s_cb, &lsA[R0 * 64]);
                }
            }
#pragma unroll
            for (int q2 = 0; q2 < 4; ++q2) {
                int r = wave * 32 + g * 16 + q2 * 4 + lr4;
                *(u16x4*)&lsB[idx64(r, cbs) + hf] = f2bf4(v[q2]);
            }
        }
        __syncthreads();
#pragma unroll
        for (int kh = 0; kh < 2; ++kh) {
            int cb = kh * 4 + (lane >> 4);
            bf16x8 afr[4];
#pragma unroll
            for (int mi = 0; mi < 4; ++mi)
                afr[mi] = *(const bf16x8*)&lsA[idx64(wm * 64 + mi * 16 + (lane & 15), cb)];
#pragma unroll
            for (int ni = 0; ni < 4; ++ni) {
                bf16x8 bfr = *(const bf16x8*)&lsB[idx64(wn * 64 + ni * 16 + (lane & 15), cb)];
#pragma unroll
                for (int mi = 0; mi < 4; ++mi)
                    acc[mi][ni] = __builtin_amdgcn_mfma_f32_16x16x32_bf16(
                        afr[mi], bfr, acc[mi][ni], 0, 0, 0);
            }
        }
        __syncthreads();
    }
#pragma unroll
    for (int mi = 0; mi < 4; ++mi)
#pragma unroll
        for (int i = 0; i < 4; ++i) {
            int rl = wm * 64 + mi * 16 + (lane >> 4) * 4 + i;
            if (rl < mmax) {
                u16* yrow = yb + (size_t)(row0 + rl) * DMODEL;
#pragma unroll
                for (int ni = 0; ni < 4; ++ni) {
                    int col = n0 + wn * 64 + ni * 16 + (lane & 15);
                    yrow[col] = f2bf(acc[mi][ni][i]);
                }
            }
        }
}

// ---------------- combine: out[t] = g0*(y0a+y0b) + g1*(y1a+y1b) ----------------
__global__ void combine_kernel(const u16* __restrict__ ybA, const u16* __restrict__ ybB,
                               const int* __restrict__ inv, const float* __restrict__ tok_gate,
                               float* __restrict__ out) {
    int t = blockIdx.x;
    int tid = threadIdx.x;                // 256
    __shared__ int sr0, sr1;
    __shared__ float sg0, sg1;
    if (tid == 0) {
        sr0 = inv[t * 2];  sr1 = inv[t * 2 + 1];
        sg0 = tok_gate[t * 2];  sg1 = tok_gate[t * 2 + 1];
    }
    __syncthreads();
    int d = tid * 4;
    u16x4 a0 = *(const u16x4*)(ybA + (size_t)sr0 * DMODEL + d);
    u16x4 b0 = *(const u16x4*)(ybB + (size_t)sr0 * DMODEL + d);
    u16x4 a1 = *(const u16x4*)(ybA + (size_t)sr1 * DMODEL + d);
    u16x4 b1 = *(const u16x4*)(ybB + (size_t)sr1 * DMODEL + d);
    float4 o;
    o.x = sg0 * (bf2f(a0.x) + bf2f(b0.x)) + sg1 * (bf2f(a1.x) + bf2f(b1.x));
    o.y = sg0 * (bf2f(a0.y) + bf2f(b0.y)) + sg1 * (bf2f(a1.y) + bf2f(b1.y));
    o.z = sg0 * (bf2f(a0.z) + bf2f(b0.z)) + sg1 * (bf2f(a1.z) + bf2f(b1.z));
    o.w = sg0 * (bf2f(a0.w) + bf2f(b0.w)) + sg1 * (bf2f(a1.w) + bf2f(b1.w));
    *(float4*)(out + (size_t)t * DMODEL + d) = o;
}

// ---------------- launch ----------------
extern "C" void kernel_launch(void* const* d_in, const int* in_sizes, int n_in,
                              void* d_out, int out_size, void* d_ws, size_t ws_size,
                              hipStream_t stream) {
    const float* x    = (const float*)d_in[0];   // [4096, 1024]
    const float* rw   = (const float*)d_in[1];   // [8, 1024]
    const float* win  = (const float*)d_in[2];   // [8, 4096, 1024]
    const float* wout = (const float*)d_in[3];   // [8, 1024, 2048]
    float* out    = (float*)d_out;               // [4096, 1024]
    float* logits = out + (size_t)N_TOK * DMODEL; // [4096, 8]

    char* ws = (char*)d_ws;
    size_t o = 0;
    auto alloc = [&](size_t bytes) -> void* {
        void* p = ws + o;
        o = (o + bytes + 255) & ~(size_t)255;
        return p;
    };
    u16*   Abf      = (u16*)  alloc((size_t)ROWS_PAD * DMODEL * 2);        // 17.0 MB
    u16*   actbuf   = (u16*)  alloc((size_t)ROWS_PAD * DFF * 2);           // 34.1 MB
    u16*   ybA      = (u16*)  alloc((size_t)ROWS_PAD * DMODEL * 2);        // 17.0 MB
    u16*   ybB      = (u16*)  alloc((size_t)ROWS_PAD * DMODEL * 2);        // 17.0 MB
    int*   offs     = (int*)  alloc(16 * 4);
    int*   inv      = (int*)  alloc(N_SLOTS * 4);
    int*   tok_exp  = (int*)  alloc(N_SLOTS * 4);
    float* tok_gate = (float*)alloc(N_SLOTS * 4);
    int*   tiletab  = (int*)  alloc((4 + MAX_TILES * 4) * 4);
    (void)ws_size; (void)in_sizes; (void)n_in; (void)out_size;

    router_kernel<<<RTR_BLOCKS, 256, 0, stream>>>(x, rw, logits, tok_exp, tok_gate);
    scan_kernel<<<1, 256, 0, stream>>>(tok_exp, offs, inv, tiletab);
    gather_kernel<<<N_TOK, 256, 0, stream>>>(x, inv, Abf);
    gemm1_kernel<<<MAX_TILES * 32, 256, 0, stream>>>(Abf, win, actbuf, tiletab);
    gemm2_kernel<<<MAX_TILES * 16, 256, 0, stream>>>(actbuf, wout, ybA, ybB, tiletab);
    combine_kernel<<<N_TOK, 256, 0, stream>>>(ybA, ybB, inv, tok_gate, out);
}

// Round 3
// 428.833 us; speedup vs baseline: 1.1728x; 1.1728x over previous
//
#include <hip/hip_runtime.h>
#include <stdint.h>

#define N_TOK   4096
#define DMODEL  1024
#define DFF     2048
#define N_EXP   8
#define N_SLOTS (N_TOK * 2)        // 8192 (every token has exactly 2 expert slots)
#define ROWS_PAD (N_SLOTS + 128)   // padding so tile-tail OOB reads stay in-bounds
#define MAX_TILES 72               // sum ceil(cnt_e/128) <= 71 for any routing

typedef __bf16 bf16x8 __attribute__((ext_vector_type(8)));
typedef float  f32x4  __attribute__((ext_vector_type(4)));
typedef unsigned short u16;
typedef unsigned short u16x4 __attribute__((ext_vector_type(4)));

__device__ __forceinline__ u16 f2bf(float f) {
    union { float f; uint32_t u; } v; v.f = f;
    uint32_t r = v.u + 0x7FFFu + ((v.u >> 16) & 1u);  // RTNE
    return (u16)(r >> 16);
}
__device__ __forceinline__ float bf2f(u16 u) {
    union { uint32_t u; float f; } v; v.u = ((uint32_t)u) << 16;
    return v.f;
}

// async 16B/lane global->LDS. LDS dest is wave-uniform base + lane*16 (m104 caveat).
__device__ __forceinline__ void g2l16(const void* gp, void* lp) {
    auto g = reinterpret_cast<const __attribute__((address_space(1))) unsigned int*>(
        reinterpret_cast<uintptr_t>(gp));
    auto l = reinterpret_cast<__attribute__((address_space(3))) unsigned int*>(
        reinterpret_cast<uintptr_t>(lp));
    __builtin_amdgcn_global_load_lds(g, l, 16, 0, 0);
}

// ---- XOR swizzle for 64-u16-wide (128B-row) LDS tiles: 8 col-blocks of 16B ----
// slot(r,cb) = cb ^ (r&7). Verified R6/R7: SQ_LDS_BANK_CONFLICT == 0.
__device__ __forceinline__ int idx64(int r, int cb) {
    return r * 64 + ((cb ^ (r & 7)) * 8);
}

// R10 schedule: cvt is hidden, not optimized (R0/R8 both pinned it at 2.1 TB/s / 98us).
//  D1 router | D2 scan | D3 gather + win-cvt (fused blocks) |
//  D4 gemm1 + wout-cvt (fused blocks, wout not needed until gemm2) | D5 gemm2 | D6 combine
#define RTR_BLOCKS (N_TOK / 4)                    // 1024 (4 waves/block, 1 token/wave)
#define WCVT1_BLOCKS 2048
#define WCVT1_THREADS (WCVT1_BLOCKS * 256)        // 524288
#define NV4_WIN  (N_EXP * 2 * DFF * DMODEL / 4)   // 8388608  (16 iters, exact)
#define WCVT2_BLOCKS 1024
#define WCVT2_THREADS (WCVT2_BLOCKS * 256)        // 262144
#define NV4_WOUT (N_EXP * DMODEL * DFF / 4)       // 4194304  (16 iters, exact)
#define GEMM1_GRID (MAX_TILES * 32)               // 2304

// ---------------- router ----------------
__global__ void router_kernel(const float* __restrict__ x, const float* __restrict__ rw,
                              float* __restrict__ logits, int* __restrict__ tok_expert,
                              float* __restrict__ tok_gate) {
    int t = blockIdx.x * 4 + (threadIdx.x >> 6);
    int lane = threadIdx.x & 63;
    const float* xr = x + (size_t)t * DMODEL;
    float acc[N_EXP];
#pragma unroll
    for (int e = 0; e < N_EXP; ++e) acc[e] = 0.f;
    for (int i = 0; i < DMODEL / 64; ++i) {
        int k = lane + i * 64;
        float xv = xr[k];
#pragma unroll
        for (int e = 0; e < N_EXP; ++e) acc[e] += xv * rw[e * DMODEL + k];
    }
#pragma unroll
    for (int e = 0; e < N_EXP; ++e) {
        float v = acc[e];
        for (int off = 32; off > 0; off >>= 1) v += __shfl_down(v, off, 64);
        acc[e] = v;
    }
    if (lane == 0) {
        float* lg = logits + (size_t)t * N_EXP;
#pragma unroll
        for (int e = 0; e < N_EXP; ++e) lg[e] = acc[e];
        int e0 = 0; float v0 = acc[0];
#pragma unroll
        for (int e = 1; e < N_EXP; ++e) if (acc[e] > v0) { v0 = acc[e]; e0 = e; }
        int e1 = -1; float v1 = -3.0e38f;
#pragma unroll
        for (int e = 0; e < N_EXP; ++e) if (e != e0 && acc[e] > v1) { v1 = acc[e]; e1 = e; }
        float ex = expf(v1 - v0);
        tok_expert[t * 2 + 0] = e0;  tok_gate[t * 2 + 0] = 1.0f / (1.0f + ex);
        tok_expert[t * 2 + 1] = e1;  tok_gate[t * 2 + 1] = ex / (1.0f + ex);
    }
}

// ---------------- scan: counting sort -> offs[], inv[], flat m-tile table ----------------
__global__ void scan_kernel(const int* __restrict__ tok_expert, int* __restrict__ offs,
                            int* __restrict__ inv, int* __restrict__ tiletab) {
    __shared__ int cnt[N_EXP][257];   // [e][t] per-thread counts; [e][256] = expert total
    __shared__ int soffs[N_EXP];
    int tid = threadIdx.x;            // 256
    int base = tid * 32;
    int loc[N_EXP];
#pragma unroll
    for (int e = 0; e < N_EXP; ++e) loc[e] = 0;
    for (int i = 0; i < 32; ++i) {
        int ex = tok_expert[base + i];
#pragma unroll
        for (int e = 0; e < N_EXP; ++e) loc[e] += (ex == e);
    }
#pragma unroll
    for (int e = 0; e < N_EXP; ++e) cnt[e][tid] = loc[e];
    __syncthreads();
    if (tid < N_EXP) {                // serial exclusive prefix over 256 thread-counts
        int running = 0;
        for (int t = 0; t < 256; ++t) { int c = cnt[tid][t]; cnt[tid][t] = running; running += c; }
        cnt[tid][256] = running;
    }
    __syncthreads();
    if (tid == 0) {
        int s = 0;
        for (int e = 0; e < N_EXP; ++e) { offs[e] = s; soffs[e] = s; s += cnt[e][256]; }
        offs[N_EXP] = s;
        int n = 0;
        for (int e = 0; e < N_EXP; ++e) {
            int c = cnt[e][256];
            int r0 = soffs[e];
            for (int m = 0; m * 128 < c; ++m) {
                int rem = c - m * 128;
                tiletab[4 + n * 4 + 0] = e;
                tiletab[4 + n * 4 + 1] = r0 + m * 128;
                tiletab[4 + n * 4 + 2] = rem < 128 ? rem : 128;
                ++n;
            }
        }
        tiletab[0] = n;
    }
    __syncthreads();
#pragma unroll
    for (int e = 0; e < N_EXP; ++e) loc[e] = 0;   // reuse as local rank counters
    for (int i = 0; i < 32; ++i) {
        int ex = tok_expert[base + i];
        int row = 0;
#pragma unroll
        for (int e = 0; e < N_EXP; ++e)
            if (ex == e) { row = soffs[e] + cnt[e][tid] + loc[e]; loc[e]++; }
        inv[base + i] = row;
    }
}

// ---------------- gather + win-cvt (fused dispatch) ----------------
// blocks [0, N_TOK): token gather (drain in ~5us). blocks [N_TOK, +WCVT1): persistent
// grid-stride fp32->bf16 cvt of win (the long pole; must finish before gemm1).
__global__ void gather_cvt_kernel(const float* __restrict__ x, const int* __restrict__ inv,
                                  u16* __restrict__ Abf,
                                  const float4* __restrict__ win, u16x4* __restrict__ winbf4) {
    int bid = blockIdx.x;
    if (bid < N_TOK) {
        int t = bid;                      // token
        int r0 = inv[t * 2];
        int r1 = inv[t * 2 + 1];
        float4 v = ((const float4*)(x + (size_t)t * DMODEL))[threadIdx.x];
        u16x4 o = { f2bf(v.x), f2bf(v.y), f2bf(v.z), f2bf(v.w) };
        *(u16x4*)(Abf + (size_t)r0 * DMODEL + threadIdx.x * 4) = o;
        *(u16x4*)(Abf + (size_t)r1 * DMODEL + threadIdx.x * 4) = o;
        return;
    }
    int g = (bid - N_TOK) * 256 + threadIdx.x;
#pragma unroll 4
    for (int i = g; i < NV4_WIN; i += WCVT1_THREADS) {
        float4 a = win[i];
        u16x4 o = { f2bf(a.x), f2bf(a.y), f2bf(a.z), f2bf(a.w) };
        winbf4[i] = o;
    }
}

// ---------------- GEMM1 + wout-cvt: act = silu(A @ Win1^T) * (A @ Win2^T) ----------------
// BM=128 x BN=64 act-cols (x2 SwiGLU halves), BK=64. One m-tile per block via tiletab.
// Grid GEMM1_GRID gemm blocks (nt fastest: adjacent blocks share the A-tile in L2)
// + WCVT2 trailing blocks converting wout (only needed by gemm2) under gemm1's tail.
__global__ __launch_bounds__(256, 4)
void gemm1_kernel(const u16* __restrict__ Abf, const u16* __restrict__ winbf,
                  u16* __restrict__ act, const int* __restrict__ tiletab,
                  const float4* __restrict__ wout, u16x4* __restrict__ woutbf4) {
    int bid = blockIdx.x;
    if (bid >= GEMM1_GRID) {              // wout-cvt blocks
        int g = (bid - GEMM1_GRID) * 256 + threadIdx.x;
#pragma unroll 4
        for (int i = g; i < NV4_WOUT; i += WCVT2_THREADS) {
            float4 a = wout[i];
            u16x4 o = { f2bf(a.x), f2bf(a.y), f2bf(a.z), f2bf(a.w) };
            woutbf4[i] = o;
        }
        return;
    }
    int nt = bid & 31;
    int ti = bid >> 5;
    if (ti >= tiletab[0]) return;
    int e    = tiletab[4 + ti * 4 + 0];
    int row0 = tiletab[4 + ti * 4 + 1];
    int mmax = tiletab[4 + ti * 4 + 2];
    int n0 = nt * 64;
    const u16* wb = winbf + (size_t)e * (2 * DFF) * DMODEL;

    __shared__ u16 lsA[128 * 64];
    __shared__ u16 lsB[2][64 * 64];

    int tid = threadIdx.x, lane = tid & 63, wave = tid >> 6;
    int wm = wave >> 1, wn = wave & 1;
    int s_r8 = lane >> 3;                       // row within 8-row chunk
    int s_cb = ((lane & 7) ^ (lane >> 3)) * 8;  // swizzled source col-block (elements)

    f32x4 acc[2][4][2];
    f32x4 zero = {0.f, 0.f, 0.f, 0.f};
#pragma unroll
    for (int h = 0; h < 2; ++h)
#pragma unroll
        for (int mi = 0; mi < 4; ++mi)
#pragma unroll
            for (int ni = 0; ni < 2; ++ni) acc[h][mi][ni] = zero;

    for (int kk = 0; kk < DMODEL / 64; ++kk) {
        int k0 = kk * 64;
#pragma unroll
        for (int q = 0; q < 4; ++q) {
            int R0 = wave * 32 + q * 8;
            g2l16(Abf + (size_t)(row0 + R0 + s_r8) * DMODEL + k0 + s_cb, &lsA[R0 * 64]);
        }
#pragma unroll
        for (int h = 0; h < 2; ++h)
#pragma unroll
            for (int q = 0; q < 2; ++q) {
                int R0 = wave * 16 + q * 8;
                g2l16(wb + (size_t)(h * DFF + n0 + R0 + s_r8) * DMODEL + k0 + s_cb,
                      &lsB[h][R0 * 64]);
            }
        __syncthreads();
#pragma unroll
        for (int kh = 0; kh < 2; ++kh) {
            int cb = kh * 4 + (lane >> 4);
            bf16x8 afr[4];
#pragma unroll
            for (int mi = 0; mi < 4; ++mi)
                afr[mi] = *(const bf16x8*)&lsA[idx64(wm * 64 + mi * 16 + (lane & 15), cb)];
#pragma unroll
            for (int h = 0; h < 2; ++h)
#pragma unroll
                for (int ni = 0; ni < 2; ++ni) {
                    bf16x8 bfr = *(const bf16x8*)&lsB[h][idx64(wn * 32 + ni * 16 + (lane & 15), cb)];
#pragma unroll
                    for (int mi = 0; mi < 4; ++mi)
                        acc[h][mi][ni] = __builtin_amdgcn_mfma_f32_16x16x32_bf16(
                            afr[mi], bfr, acc[h][mi][ni], 0, 0, 0);
                }
        }
        __syncthreads();
    }
    // epilogue: act = silu(h1) * h2, store bf16
#pragma unroll
    for (int mi = 0; mi < 4; ++mi)
#pragma unroll
        for (int i = 0; i < 4; ++i) {
            int rl = wm * 64 + mi * 16 + (lane >> 4) * 4 + i;
            if (rl < mmax) {
                size_t rp = (size_t)(row0 + rl) * DFF;
#pragma unroll
                for (int ni = 0; ni < 2; ++ni) {
                    int col = n0 + wn * 32 + ni * 16 + (lane & 15);
                    float a = acc[0][mi][ni][i];
                    float b = acc[1][mi][ni][i];
                    float sv = a / (1.0f + __expf(-a));
                    act[rp + col] = f2bf(sv * b);
                }
            }
        }
}

// ---------------- GEMM2: y = act @ Wout^T, split-K=2, bf16 stores ----------------
// BM=128 x BN=128, BK=64, K=1024 per kc. One m-tile per block via tiletab.
// Grid MAX_TILES x 8 nt x 2 kc (nt/kc fastest: 16 adjacent blocks share the act-tile).
__global__ __launch_bounds__(256, 4)
void gemm2_kernel(const u16* __restrict__ act, const u16* __restrict__ woutbf,
                  u16* __restrict__ ybA, u16* __restrict__ ybB,
                  const int* __restrict__ tiletab) {
    int bid = blockIdx.x;
    int kc = bid & 1;
    int nt = (bid >> 1) & 7;
    int ti = bid >> 4;
    if (ti >= tiletab[0]) return;
    int e    = tiletab[4 + ti * 4 + 0];
    int row0 = tiletab[4 + ti * 4 + 1];
    int mmax = tiletab[4 + ti * 4 + 2];
    int n0 = nt * 128;
    const u16* wb = woutbf + (size_t)e * DMODEL * DFF;

    __shared__ u16 lsA[128 * 64];
    __shared__ u16 lsB[128 * 64];

    int tid = threadIdx.x, lane = tid & 63, wave = tid >> 6;
    int wm = wave >> 1, wn = wave & 1;
    int s_r8 = lane >> 3;
    int s_cb = ((lane & 7) ^ (lane >> 3)) * 8;
    u16* yb = kc ? ybB : ybA;

    f32x4 acc[4][4];
    f32x4 zero = {0.f, 0.f, 0.f, 0.f};
#pragma unroll
    for (int mi = 0; mi < 4; ++mi)
#pragma unroll
        for (int ni = 0; ni < 4; ++ni) acc[mi][ni] = zero;

    for (int kk = kc * 16; kk < kc * 16 + 16; ++kk) {
        int k0 = kk * 64;
#pragma unroll
        for (int q = 0; q < 4; ++q) {
            int R0 = wave * 32 + q * 8;
            g2l16(act + (size_t)(row0 + R0 + s_r8) * DFF + k0 + s_cb, &lsA[R0 * 64]);
            g2l16(wb + (size_t)(n0 + R0 + s_r8) * DFF + k0 + s_cb, &lsB[R0 * 64]);
        }
        __syncthreads();
#pragma unroll
        for (int kh = 0; kh < 2; ++kh) {
            int cb = kh * 4 + (lane >> 4);
            bf16x8 afr[4];
#pragma unroll
            for (int mi = 0; mi < 4; ++mi)
                afr[mi] = *(const bf16x8*)&lsA[idx64(wm * 64 + mi * 16 + (lane & 15), cb)];
#pragma unroll
            for (int ni = 0; ni < 4; ++ni) {
                bf16x8 bfr = *(const bf16x8*)&lsB[idx64(wn * 64 + ni * 16 + (lane & 15), cb)];
#pragma unroll
                for (int mi = 0; mi < 4; ++mi)
                    acc[mi][ni] = __builtin_amdgcn_mfma_f32_16x16x32_bf16(
                        afr[mi], bfr, acc[mi][ni], 0, 0, 0);
            }
        }
        __syncthreads();
    }
#pragma unroll
    for (int mi = 0; mi < 4; ++mi)
#pragma unroll
        for (int i = 0; i < 4; ++i) {
            int rl = wm * 64 + mi * 16 + (lane >> 4) * 4 + i;
            if (rl < mmax) {
                u16* yrow = yb + (size_t)(row0 + rl) * DMODEL;
#pragma unroll
                for (int ni = 0; ni < 4; ++ni) {
                    int col = n0 + wn * 64 + ni * 16 + (lane & 15);
                    yrow[col] = f2bf(acc[mi][ni][i]);
                }
            }
        }
}

// ---------------- combine: out[t] = g0*(y0a+y0b) + g1*(y1a+y1b) ----------------
__global__ void combine_kernel(const u16* __restrict__ ybA, const u16* __restrict__ ybB,
                               const int* __restrict__ inv, const float* __restrict__ tok_gate,
                               float* __restrict__ out) {
    int t = blockIdx.x;
    int tid = threadIdx.x;                // 256
    __shared__ int sr0, sr1;
    __shared__ float sg0, sg1;
    if (tid == 0) {
        sr0 = inv[t * 2];  sr1 = inv[t * 2 + 1];
        sg0 = tok_gate[t * 2];  sg1 = tok_gate[t * 2 + 1];
    }
    __syncthreads();
    int d = tid * 4;
    u16x4 a0 = *(const u16x4*)(ybA + (size_t)sr0 * DMODEL + d);
    u16x4 b0 = *(const u16x4*)(ybB + (size_t)sr0 * DMODEL + d);
    u16x4 a1 = *(const u16x4*)(ybA + (size_t)sr1 * DMODEL + d);
    u16x4 b1 = *(const u16x4*)(ybB + (size_t)sr1 * DMODEL + d);
    float4 o;
    o.x = sg0 * (bf2f(a0.x) + bf2f(b0.x)) + sg1 * (bf2f(a1.x) + bf2f(b1.x));
    o.y = sg0 * (bf2f(a0.y) + bf2f(b0.y)) + sg1 * (bf2f(a1.y) + bf2f(b1.y));
    o.z = sg0 * (bf2f(a0.z) + bf2f(b0.z)) + sg1 * (bf2f(a1.z) + bf2f(b1.z));
    o.w = sg0 * (bf2f(a0.w) + bf2f(b0.w)) + sg1 * (bf2f(a1.w) + bf2f(b1.w));
    *(float4*)(out + (size_t)t * DMODEL + d) = o;
}

// ---------------- launch ----------------
extern "C" void kernel_launch(void* const* d_in, const int* in_sizes, int n_in,
                              void* d_out, int out_size, void* d_ws, size_t ws_size,
                              hipStream_t stream) {
    const float* x    = (const float*)d_in[0];   // [4096, 1024]
    const float* rw   = (const float*)d_in[1];   // [8, 1024]
    const float* win  = (const float*)d_in[2];   // [8, 4096, 1024]
    const float* wout = (const float*)d_in[3];   // [8, 1024, 2048]
    float* out    = (float*)d_out;               // [4096, 1024]
    float* logits = out + (size_t)N_TOK * DMODEL; // [4096, 8]

    char* ws = (char*)d_ws;
    size_t o = 0;
    auto alloc = [&](size_t bytes) -> void* {
        void* p = ws + o;
        o = (o + bytes + 255) & ~(size_t)255;
        return p;
    };
    u16*   Abf      = (u16*)  alloc((size_t)ROWS_PAD * DMODEL * 2);        // 17.0 MB
    u16*   actbuf   = (u16*)  alloc((size_t)ROWS_PAD * DFF * 2);           // 34.1 MB
    u16*   winbf    = (u16*)  alloc((size_t)N_EXP * 2 * DFF * DMODEL * 2); // 67.1 MB
    u16*   woutbf   = (u16*)  alloc((size_t)N_EXP * DMODEL * DFF * 2);     // 33.6 MB
    int*   offs     = (int*)  alloc(16 * 4);
    int*   inv      = (int*)  alloc(N_SLOTS * 4);
    int*   tok_exp  = (int*)  alloc(N_SLOTS * 4);
    float* tok_gate = (float*)alloc(N_SLOTS * 4);
    int*   tiletab  = (int*)  alloc((4 + MAX_TILES * 4) * 4);
    // ybA/ybB alias winbf: winbf is dead after gemm1, yb needs 2x17 MB
    u16*   ybA      = winbf;
    u16*   ybB      = winbf + (size_t)ROWS_PAD * DMODEL;
    (void)ws_size; (void)in_sizes; (void)n_in; (void)out_size;

    router_kernel<<<RTR_BLOCKS, 256, 0, stream>>>(x, rw, logits, tok_exp, tok_gate);
    scan_kernel<<<1, 256, 0, stream>>>(tok_exp, offs, inv, tiletab);
    gather_cvt_kernel<<<N_TOK + WCVT1_BLOCKS, 256, 0, stream>>>(
        x, inv, Abf, (const float4*)win, (u16x4*)winbf);
    gemm1_kernel<<<GEMM1_GRID + WCVT2_BLOCKS, 256, 0, stream>>>(
        Abf, winbf, actbuf, tiletab, (const float4*)wout, (u16x4*)woutbf);
    gemm2_kernel<<<MAX_TILES * 16, 256, 0, stream>>>(actbuf, woutbf, ybA, ybB, tiletab);
    combine_kernel<<<N_TOK, 256, 0, stream>>>(ybA, ybB, inv, tok_gate, out);
}